// Round 1
// baseline (2138.284 us; speedup 1.0000x reference)
//
#include <hip/hip_runtime.h>
#include <hip/hip_bf16.h>
#include <cstdint>
#include <cstddef>

// Problem constants (B=4,T=2048 -> 8192 tokens)
#define DD   1024
#define FF   4096
#define EE   8
#define NTOK 8192
#define PAIRS (NTOK*2)

typedef short bf16x8 __attribute__((ext_vector_type(8)));
typedef float f32x4  __attribute__((ext_vector_type(4)));

// ---- workspace layout (bytes). Total needed ~151.3 MB ----
#define WS_COUNTS   0u                         // 8 u32
#define WS_CURSORS  64u                        // 8 u32
#define WS_OFFSETS  128u                       // 8 u32
#define WS_SUMPART  256u                       // 64*8 f32
#define WS_TOKTOP   4096u                      // NTOK * 16B (w0,w1,i0,i1)
#define WS_SLOTTOK  (WS_TOKTOP + NTOK*16u)     // PAIRS * 4
#define WS_SLOTW    (WS_SLOTTOK + PAIRS*4u)    // PAIRS * 4
#define WS_XBF      (WS_SLOTW + PAIRS*4u)      // NTOK*DD*2 (bf16 x)
#define WS_H        (WS_XBF + (size_t)NTOK*DD*2u) // PAIRS*FF*2 (bf16 h)

__device__ __forceinline__ unsigned short f2bf(float f) {
    union { float f; unsigned u; } v; v.f = f;
    unsigned r = v.u + 0x7fffu + ((v.u >> 16) & 1u);   // RNE
    return (unsigned short)(r >> 16);
}

// ---------------- x fp32 -> bf16 ----------------
__global__ __launch_bounds__(256) void k_convert_x(const float* __restrict__ x,
                                                   ushort* __restrict__ xb) {
    int n4 = NTOK * DD / 4;
    int i = blockIdx.x * 256 + threadIdx.x;
    int stride = gridDim.x * 256;
    for (; i < n4; i += stride) {
        float4 v = ((const float4*)x)[i];
        ushort4 o;
        o.x = f2bf(v.x); o.y = f2bf(v.y); o.z = f2bf(v.z); o.w = f2bf(v.w);
        ((ushort4*)xb)[i] = o;
    }
}

// ---------------- router: logits -> softmax -> top2 ----------------
// one wave per token; 4 waves/block
__global__ __launch_bounds__(256) void k_router(const float* __restrict__ x,
                                                const float* __restrict__ gw,
                                                float4* __restrict__ toktop,
                                                unsigned* __restrict__ counts,
                                                float* __restrict__ sumpart) {
    __shared__ float bsum[8];
    __shared__ unsigned bcnt[8];
    int lane = threadIdx.x & 63;
    int wid  = threadIdx.x >> 6;
    if (threadIdx.x < 8) { bsum[threadIdx.x] = 0.f; bcnt[threadIdx.x] = 0u; }
    __syncthreads();

    int t = blockIdx.x * 4 + wid;
    float p[8] = {0,0,0,0,0,0,0,0};
    const float* xr = x + (size_t)t * DD;
    #pragma unroll
    for (int j = 0; j < 16; j++) {
        int d = lane + j * 64;
        float xv = xr[d];
        const float4 g0 = ((const float4*)(gw + (size_t)d * 8))[0];
        const float4 g1 = ((const float4*)(gw + (size_t)d * 8))[1];
        p[0] += xv * g0.x; p[1] += xv * g0.y; p[2] += xv * g0.z; p[3] += xv * g0.w;
        p[4] += xv * g1.x; p[5] += xv * g1.y; p[6] += xv * g1.z; p[7] += xv * g1.w;
    }
    #pragma unroll
    for (int e = 0; e < 8; e++)
        #pragma unroll
        for (int off = 32; off; off >>= 1) p[e] += __shfl_xor(p[e], off);

    // softmax over 8 (all lanes redundantly)
    float mx = p[0];
    #pragma unroll
    for (int e = 1; e < 8; e++) mx = fmaxf(mx, p[e]);
    float s = 0.f;
    #pragma unroll
    for (int e = 0; e < 8; e++) { p[e] = expf(p[e] - mx); s += p[e]; }
    float inv = 1.f / s;
    #pragma unroll
    for (int e = 0; e < 8; e++) p[e] *= inv;

    // top-2 (earliest index on ties, matching lax.top_k)
    int i0 = 0; float p0 = p[0];
    #pragma unroll
    for (int e = 1; e < 8; e++) if (p[e] > p0) { p0 = p[e]; i0 = e; }
    int i1 = (i0 == 0) ? 1 : 0; float p1 = p[i1];
    #pragma unroll
    for (int e = 0; e < 8; e++) if (e != i0 && p[e] > p1) { p1 = p[e]; i1 = e; }

    if (lane == 0) {
        float wsum = p0 + p1 + 1e-9f;
        float4 tt;
        tt.x = p0 / wsum; tt.y = p1 / wsum;
        tt.z = __int_as_float(i0); tt.w = __int_as_float(i1);
        toktop[t] = tt;
        atomicAdd(&bcnt[i0], 1u);
        atomicAdd(&bcnt[i1], 1u);
        #pragma unroll
        for (int e = 0; e < 8; e++) atomicAdd(&bsum[e], p[e]);
    }
    __syncthreads();
    if (threadIdx.x < 8) {
        atomicAdd(&sumpart[(blockIdx.x & 63) * 8 + threadIdx.x], bsum[threadIdx.x]);
        if (bcnt[threadIdx.x]) atomicAdd(&counts[threadIdx.x], bcnt[threadIdx.x]);
    }
}

// ---------------- offsets (prefix over 8) ----------------
__global__ void k_offsets(const unsigned* __restrict__ counts, unsigned* __restrict__ offsets) {
    if (threadIdx.x == 0) {
        unsigned o = 0;
        for (int e = 0; e < 8; e++) { offsets[e] = o; o += counts[e]; }
    }
}

// ---------------- scatter tokens into per-expert slot lists ----------------
__global__ __launch_bounds__(256) void k_scatter(const float4* __restrict__ toktop,
                                                 const unsigned* __restrict__ offsets,
                                                 unsigned* __restrict__ cursors,
                                                 int* __restrict__ slot_tok,
                                                 float* __restrict__ slot_w) {
    int t = blockIdx.x * 256 + threadIdx.x;
    int lane = threadIdx.x & 63;
    float4 tt = toktop[t];
    int   idx[2] = { __float_as_int(tt.z), __float_as_int(tt.w) };
    float wv[2]  = { tt.x, tt.y };
    #pragma unroll
    for (int k = 0; k < 2; k++) {
        int e = idx[k];
        #pragma unroll
        for (int ee = 0; ee < 8; ee++) {
            unsigned long long m = __ballot(e == ee);
            if (e == ee) {
                int leader = __builtin_ctzll(m);
                int prefix = __popcll(m & ((1ull << lane) - 1ull));
                unsigned b = 0;
                if (lane == leader) b = atomicAdd(&cursors[ee], (unsigned)__popcll(m));
                b = __shfl(b, leader);
                int slot = (int)offsets[ee] + (int)b + prefix;
                slot_tok[slot] = t;
                slot_w[slot]   = wv[k];
            }
        }
    }
}

// ---------------- FFN layer 1: h = gelu(gather(x) @ w1[e] + b1[e]) ----------------
// tile 128x128, BK=64, 4 waves (2x2), mfma 16x16x32 bf16
__global__ __launch_bounds__(256, 2) void k_ffn1(const ushort* __restrict__ xb,
                                                 const float* __restrict__ w1,
                                                 const float* __restrict__ b1,
                                                 const int* __restrict__ slot_tok,
                                                 const unsigned* __restrict__ counts,
                                                 const unsigned* __restrict__ offsets,
                                                 ushort* __restrict__ h) {
    const int e   = blockIdx.z;
    const int cnt = (int)counts[e];
    const int m0  = blockIdx.y * 128;
    if (m0 >= cnt) return;
    const int n0   = blockIdx.x * 128;
    const int base = (int)offsets[e] + m0;

    __shared__ __align__(16) char ldsA[128 * 128];  // [row 0..127][64 bf16], row=128B, xor-swz
    __shared__ __align__(16) char ldsB[128 * 128];  // [n 0..127][64 bf16] (B^T), xor-swz

    const int tid  = threadIdx.x;
    const int lane = tid & 63;
    const int wid  = tid >> 6;
    const int wr = wid >> 1, wc = wid & 1;

    f32x4 acc[4][4] = {};

    const int arow = tid >> 1, ahalf = tid & 1;
    const int grow = (m0 + arow < cnt) ? arow : 0;                  // clamp tail rows
    const size_t tok = (size_t)slot_tok[base + grow];
    const ushort* asrc = xb + tok * DD + ahalf * 32;

    const int c4 = tid & 31, kr0 = tid >> 5;
    const float* w1e = w1 + (size_t)e * DD * FF + n0;

    for (int kt = 0; kt < DD / 64; ++kt) {
        __syncthreads();
        // stage A (bf16 gather): 4x 16B per thread
        {
            const uint4* s4 = (const uint4*)(asrc + kt * 64);
            #pragma unroll
            for (int j = 0; j < 4; j++) {
                uint4 v = s4[j];
                int off = (arow * 128 + ahalf * 64 + j * 16) ^ ((arow & 7) << 4);
                *(uint4*)(ldsA + off) = v;
            }
        }
        // stage B (fp32 -> bf16, transpose into [n][k])
        {
            #pragma unroll
            for (int i = 0; i < 8; i++) {
                int kr = kr0 + i * 8;
                float4 v = *(const float4*)(w1e + (size_t)(kt * 64 + kr) * FF + c4 * 4);
                ushort bb[4] = { f2bf(v.x), f2bf(v.y), f2bf(v.z), f2bf(v.w) };
                #pragma unroll
                for (int j = 0; j < 4; j++) {
                    int n = c4 * 4 + j;
                    *(ushort*)(ldsB + ((n * 128 + kr * 2) ^ ((n & 7) << 4))) = bb[j];
                }
            }
        }
        __syncthreads();
        // compute
        #pragma unroll
        for (int kk = 0; kk < 2; ++kk) {
            bf16x8 a[4], b[4];
            #pragma unroll
            for (int m = 0; m < 4; m++) {
                int r = wr * 64 + m * 16 + (lane & 15);
                a[m] = *(const bf16x8*)(ldsA + ((r * 128 + kk * 64 + (lane >> 4) * 16) ^ ((r & 7) << 4)));
            }
            #pragma unroll
            for (int n = 0; n < 4; n++) {
                int r = wc * 64 + n * 16 + (lane & 15);
                b[n] = *(const bf16x8*)(ldsB + ((r * 128 + kk * 64 + (lane >> 4) * 16) ^ ((r & 7) << 4)));
            }
            #pragma unroll
            for (int m = 0; m < 4; m++)
                #pragma unroll
                for (int n = 0; n < 4; n++)
                    acc[m][n] = __builtin_amdgcn_mfma_f32_16x16x32_bf16(a[m], b[n], acc[m][n], 0, 0, 0);
        }
    }

    // epilogue: bias + exact gelu -> bf16 h
    const float* b1e = b1 + (size_t)e * FF + n0;
    #pragma unroll
    for (int m = 0; m < 4; m++) {
        #pragma unroll
        for (int v = 0; v < 4; v++) {
            int lr = wr * 64 + m * 16 + (lane >> 4) * 4 + v;
            if (m0 + lr >= cnt) continue;
            size_t hrow = (size_t)(base + lr) * FF + n0;
            #pragma unroll
            for (int n = 0; n < 4; n++) {
                int col = wc * 64 + n * 16 + (lane & 15);
                float val = acc[m][n][v] + b1e[col];
                val = 0.5f * val * (1.0f + erff(val * 0.70710678118654752f));
                h[hrow + col] = f2bf(val);
            }
        }
    }
}

// ---------------- FFN layer 2: out[tok] += w * (h @ w2[e] + b2[e]) ----------------
__global__ __launch_bounds__(256, 2) void k_ffn2(const ushort* __restrict__ h,
                                                 const float* __restrict__ w2,
                                                 const float* __restrict__ b2,
                                                 const int* __restrict__ slot_tok,
                                                 const float* __restrict__ slot_w,
                                                 const unsigned* __restrict__ counts,
                                                 const unsigned* __restrict__ offsets,
                                                 float* __restrict__ out) {
    const int e   = blockIdx.z;
    const int cnt = (int)counts[e];
    const int m0  = blockIdx.y * 128;
    if (m0 >= cnt) return;
    const int n0   = blockIdx.x * 128;
    const int base = (int)offsets[e] + m0;

    __shared__ __align__(16) char ldsA[128 * 128];
    __shared__ __align__(16) char ldsB[128 * 128];

    const int tid  = threadIdx.x;
    const int lane = tid & 63;
    const int wid  = tid >> 6;
    const int wr = wid >> 1, wc = wid & 1;

    f32x4 acc[4][4] = {};

    const int arow = tid >> 1, ahalf = tid & 1;
    const int grow = (m0 + arow < cnt) ? arow : 0;
    const ushort* asrc = h + (size_t)(base + grow) * FF + ahalf * 32;

    const int c4 = tid & 31, kr0 = tid >> 5;
    const float* w2e = w2 + (size_t)e * FF * DD + n0;

    for (int kt = 0; kt < FF / 64; ++kt) {
        __syncthreads();
        {
            const uint4* s4 = (const uint4*)(asrc + kt * 64);
            #pragma unroll
            for (int j = 0; j < 4; j++) {
                uint4 v = s4[j];
                int off = (arow * 128 + ahalf * 64 + j * 16) ^ ((arow & 7) << 4);
                *(uint4*)(ldsA + off) = v;
            }
        }
        {
            #pragma unroll
            for (int i = 0; i < 8; i++) {
                int kr = kr0 + i * 8;
                float4 v = *(const float4*)(w2e + (size_t)(kt * 64 + kr) * DD + c4 * 4);
                ushort bb[4] = { f2bf(v.x), f2bf(v.y), f2bf(v.z), f2bf(v.w) };
                #pragma unroll
                for (int j = 0; j < 4; j++) {
                    int n = c4 * 4 + j;
                    *(ushort*)(ldsB + ((n * 128 + kr * 2) ^ ((n & 7) << 4))) = bb[j];
                }
            }
        }
        __syncthreads();
        #pragma unroll
        for (int kk = 0; kk < 2; ++kk) {
            bf16x8 a[4], b[4];
            #pragma unroll
            for (int m = 0; m < 4; m++) {
                int r = wr * 64 + m * 16 + (lane & 15);
                a[m] = *(const bf16x8*)(ldsA + ((r * 128 + kk * 64 + (lane >> 4) * 16) ^ ((r & 7) << 4)));
            }
            #pragma unroll
            for (int n = 0; n < 4; n++) {
                int r = wc * 64 + n * 16 + (lane & 15);
                b[n] = *(const bf16x8*)(ldsB + ((r * 128 + kk * 64 + (lane >> 4) * 16) ^ ((r & 7) << 4)));
            }
            #pragma unroll
            for (int m = 0; m < 4; m++)
                #pragma unroll
                for (int n = 0; n < 4; n++)
                    acc[m][n] = __builtin_amdgcn_mfma_f32_16x16x32_bf16(a[m], b[n], acc[m][n], 0, 0, 0);
        }
    }

    const float* b2e = b2 + (size_t)e * DD + n0;
    #pragma unroll
    for (int m = 0; m < 4; m++) {
        #pragma unroll
        for (int v = 0; v < 4; v++) {
            int lr = wr * 64 + m * 16 + (lane >> 4) * 4 + v;
            if (m0 + lr >= cnt) continue;
            int slot = base + lr;
            int tok  = slot_tok[slot];
            float wgt = slot_w[slot];
            #pragma unroll
            for (int n = 0; n < 4; n++) {
                int col = wc * 64 + n * 16 + (lane & 15);
                float val = acc[m][n][v] + b2e[col];
                atomicAdd(&out[(size_t)tok * DD + n0 + col], wgt * val);
            }
        }
    }
}

// ---------------- aux loss ----------------
__global__ void k_aux(const float* __restrict__ sumpart, float* __restrict__ out_aux) {
    __shared__ float col[8];
    int tid = threadIdx.x;  // 64 threads
    if (tid < 8) col[tid] = 0.f;
    __syncthreads();
    #pragma unroll
    for (int e = 0; e < 8; e++) atomicAdd(&col[e], sumpart[tid * 8 + e]);
    __syncthreads();
    if (tid == 0) {
        float aux = 0.f;
        for (int e = 0; e < 8; e++) {
            float d = col[e] * (1.0f / NTOK) - 0.125f;
            aux += d * d;
        }
        out_aux[0] = aux;  // mean over E * E == sum
    }
}

extern "C" void kernel_launch(void* const* d_in, const int* in_sizes, int n_in,
                              void* d_out, int out_size, void* d_ws, size_t ws_size,
                              hipStream_t stream) {
    const float* x  = (const float*)d_in[0];
    const float* gw = (const float*)d_in[1];
    const float* w1 = (const float*)d_in[2];
    const float* b1 = (const float*)d_in[3];
    const float* w2 = (const float*)d_in[4];
    const float* b2 = (const float*)d_in[5];
    float* out = (float*)d_out;
    char*  ws  = (char*)d_ws;

    unsigned* counts  = (unsigned*)(ws + WS_COUNTS);
    unsigned* cursors = (unsigned*)(ws + WS_CURSORS);
    unsigned* offsets = (unsigned*)(ws + WS_OFFSETS);
    float*    sumpart = (float*)   (ws + WS_SUMPART);
    float4*   toktop  = (float4*)  (ws + WS_TOKTOP);
    int*      slottok = (int*)     (ws + WS_SLOTTOK);
    float*    slotw   = (float*)   (ws + WS_SLOTW);
    ushort*   xb      = (ushort*)  (ws + WS_XBF);
    ushort*   hbuf    = (ushort*)  (ws + WS_H);

    // zero control block + output accumulator
    hipMemsetAsync(ws, 0, 4096, stream);
    hipMemsetAsync(d_out, 0, (size_t)out_size * sizeof(float), stream);

    k_convert_x<<<2048, 256, 0, stream>>>(x, xb);
    k_router  <<<NTOK / 4, 256, 0, stream>>>(x, gw, toktop, counts, sumpart);
    k_offsets <<<1, 64, 0, stream>>>(counts, offsets);
    k_scatter <<<NTOK / 256, 256, 0, stream>>>(toktop, offsets, cursors, slottok, slotw);
    k_ffn1    <<<dim3(FF / 128, NTOK / 128, EE), 256, 0, stream>>>(xb, w1, b1, slottok, counts, offsets, hbuf);
    k_ffn2    <<<dim3(DD / 128, NTOK / 128, EE), 256, 0, stream>>>(hbuf, w2, b2, slottok, slotw, counts, offsets, out);
    k_aux     <<<1, 64, 0, stream>>>(sumpart, out + (size_t)NTOK * DD);
}

// Round 2
// 861.221 us; speedup vs baseline: 2.4829x; 2.4829x over previous
//
#include <hip/hip_runtime.h>
#include <hip/hip_bf16.h>
#include <cstdint>
#include <cstddef>

// Problem constants (B=4,T=2048 -> 8192 tokens)
#define DD   1024
#define FF   4096
#define EE   8
#define NTOK 8192
#define PAIRS (NTOK*2)

typedef short bf16x8 __attribute__((ext_vector_type(8)));
typedef float f32x4  __attribute__((ext_vector_type(4)));

// ---- workspace layout (bytes). Total ~285 MB ----
#define WS_COUNTS   0
#define WS_CURSORS  64
#define WS_OFFSETS  128
#define WS_SUMPART  256
#define WS_TOKTOP   4096
#define WS_SLOTTOK  (WS_TOKTOP + NTOK*16)             // 135168
#define WS_SLOTW    (WS_SLOTTOK + PAIRS*4)            // 200704
#define WS_XBF      (WS_SLOTW + PAIRS*4)              // 266240
#define WS_W1T      (WS_XBF + (size_t)NTOK*DD*2)      // +16 MB
#define WS_W2T      (WS_W1T + (size_t)EE*DD*FF*2)     // +67 MB
#define WS_H        (WS_W2T + (size_t)EE*FF*DD*2)     // +67 MB (h: +134 MB)

__device__ __forceinline__ unsigned short f2bf(float f) {
    union { float f; unsigned u; } v; v.f = f;
    unsigned r = v.u + 0x7fffu + ((v.u >> 16) & 1u);   // RNE
    return (unsigned short)(r >> 16);
}

__device__ __forceinline__ void gload_lds16(const void* g, void* l) {
    __builtin_amdgcn_global_load_lds(
        (const __attribute__((address_space(1))) void*)g,
        (__attribute__((address_space(3))) void*)l, 16, 0, 0);
}

// ---------------- x fp32 -> bf16 ----------------
__global__ __launch_bounds__(256) void k_convert_x(const float* __restrict__ x,
                                                   ushort* __restrict__ xb) {
    int n4 = NTOK * DD / 4;
    int i = blockIdx.x * 256 + threadIdx.x;
    int stride = gridDim.x * 256;
    for (; i < n4; i += stride) {
        float4 v = ((const float4*)x)[i];
        ushort4 o;
        o.x = f2bf(v.x); o.y = f2bf(v.y); o.z = f2bf(v.z); o.w = f2bf(v.w);
        ((ushort4*)xb)[i] = o;
    }
}

// ---------------- weight transpose: [E][R][C] fp32 -> [E][C][R] bf16 ----------------
__global__ __launch_bounds__(256) void k_transpose(const float* __restrict__ in,
                                                   ushort* __restrict__ out,
                                                   int R, int C) {
    __shared__ ushort tile[64 * 72];   // row stride 72 ushorts = 144B (16B aligned)
    const int e = blockIdx.z;
    const int r0 = blockIdx.y * 64, c0 = blockIdx.x * 64;
    const int t = threadIdx.x;
    {
        const float* src = in + ((size_t)e * R + r0) * C + c0;
        int r = t >> 2, cq = (t & 3) * 16;
        #pragma unroll
        for (int j = 0; j < 4; j++) {
            float4 v = *(const float4*)(src + (size_t)r * C + cq + j * 4);
            ushort4 o;
            o.x = f2bf(v.x); o.y = f2bf(v.y); o.z = f2bf(v.z); o.w = f2bf(v.w);
            *(ushort4*)(tile + r * 72 + cq + j * 4) = o;
        }
    }
    __syncthreads();
    {
        int c = t >> 2, rq = (t & 3) * 16;
        ushort* dst = out + ((size_t)e * C + c0 + c) * R + r0 + rq;
        ushort buf[16];
        #pragma unroll
        for (int j = 0; j < 16; j++) buf[j] = tile[(rq + j) * 72 + c];
        *(uint4*)(dst)     = *(const uint4*)(buf);
        *(uint4*)(dst + 8) = *(const uint4*)(buf + 8);
    }
}

// ---------------- router: logits -> softmax -> top2 ----------------
__global__ __launch_bounds__(256) void k_router(const float* __restrict__ x,
                                                const float* __restrict__ gw,
                                                float4* __restrict__ toktop,
                                                unsigned* __restrict__ counts,
                                                float* __restrict__ sumpart) {
    __shared__ float bsum[8];
    __shared__ unsigned bcnt[8];
    int lane = threadIdx.x & 63;
    int wid  = threadIdx.x >> 6;
    if (threadIdx.x < 8) { bsum[threadIdx.x] = 0.f; bcnt[threadIdx.x] = 0u; }
    __syncthreads();

    int t = blockIdx.x * 4 + wid;
    float p[8] = {0,0,0,0,0,0,0,0};
    const float* xr = x + (size_t)t * DD;
    #pragma unroll
    for (int j = 0; j < 16; j++) {
        int d = lane + j * 64;
        float xv = xr[d];
        const float4 g0 = ((const float4*)(gw + (size_t)d * 8))[0];
        const float4 g1 = ((const float4*)(gw + (size_t)d * 8))[1];
        p[0] += xv * g0.x; p[1] += xv * g0.y; p[2] += xv * g0.z; p[3] += xv * g0.w;
        p[4] += xv * g1.x; p[5] += xv * g1.y; p[6] += xv * g1.z; p[7] += xv * g1.w;
    }
    #pragma unroll
    for (int e = 0; e < 8; e++)
        #pragma unroll
        for (int off = 32; off; off >>= 1) p[e] += __shfl_xor(p[e], off);

    float mx = p[0];
    #pragma unroll
    for (int e = 1; e < 8; e++) mx = fmaxf(mx, p[e]);
    float s = 0.f;
    #pragma unroll
    for (int e = 0; e < 8; e++) { p[e] = expf(p[e] - mx); s += p[e]; }
    float inv = 1.f / s;
    #pragma unroll
    for (int e = 0; e < 8; e++) p[e] *= inv;

    int i0 = 0; float p0 = p[0];
    #pragma unroll
    for (int e = 1; e < 8; e++) if (p[e] > p0) { p0 = p[e]; i0 = e; }
    int i1 = (i0 == 0) ? 1 : 0; float p1 = p[i1];
    #pragma unroll
    for (int e = 0; e < 8; e++) if (e != i0 && p[e] > p1) { p1 = p[e]; i1 = e; }

    if (lane == 0) {
        float wsum = p0 + p1 + 1e-9f;
        float4 tt;
        tt.x = p0 / wsum; tt.y = p1 / wsum;
        tt.z = __int_as_float(i0); tt.w = __int_as_float(i1);
        toktop[t] = tt;
        atomicAdd(&bcnt[i0], 1u);
        atomicAdd(&bcnt[i1], 1u);
        #pragma unroll
        for (int e = 0; e < 8; e++) atomicAdd(&bsum[e], p[e]);
    }
    __syncthreads();
    if (threadIdx.x < 8) {
        atomicAdd(&sumpart[(blockIdx.x & 63) * 8 + threadIdx.x], bsum[threadIdx.x]);
        if (bcnt[threadIdx.x]) atomicAdd(&counts[threadIdx.x], bcnt[threadIdx.x]);
    }
}

// ---------------- offsets ----------------
__global__ void k_offsets(const unsigned* __restrict__ counts, unsigned* __restrict__ offsets) {
    if (threadIdx.x == 0) {
        unsigned o = 0;
        for (int e = 0; e < 8; e++) { offsets[e] = o; o += counts[e]; }
    }
}

// ---------------- scatter ----------------
__global__ __launch_bounds__(256) void k_scatter(const float4* __restrict__ toktop,
                                                 const unsigned* __restrict__ offsets,
                                                 unsigned* __restrict__ cursors,
                                                 int* __restrict__ slot_tok,
                                                 float* __restrict__ slot_w) {
    int t = blockIdx.x * 256 + threadIdx.x;
    int lane = threadIdx.x & 63;
    float4 tt = toktop[t];
    int   idx[2] = { __float_as_int(tt.z), __float_as_int(tt.w) };
    float wv[2]  = { tt.x, tt.y };
    #pragma unroll
    for (int k = 0; k < 2; k++) {
        int e = idx[k];
        #pragma unroll
        for (int ee = 0; ee < 8; ee++) {
            unsigned long long m = __ballot(e == ee);
            if (e == ee) {
                int leader = __builtin_ctzll(m);
                int prefix = __popcll(m & ((1ull << lane) - 1ull));
                unsigned b = 0;
                if (lane == leader) b = atomicAdd(&cursors[ee], (unsigned)__popcll(m));
                b = __shfl(b, leader);
                int slot = (int)offsets[ee] + (int)b + prefix;
                slot_tok[slot] = t;
                slot_w[slot]   = wv[k];
            }
        }
    }
}

// ---------------- FFN1: h = gelu(gather(xb) @ w1t^T + b1) ----------------
// 128x128 tile, BK=64, 4 waves (2x2), global_load_lds staging (pre-swizzled src)
__global__ __launch_bounds__(256, 2) void k_ffn1(const ushort* __restrict__ xb,
                                                 const ushort* __restrict__ w1t,  // [E][F][D] bf16
                                                 const float* __restrict__ b1,
                                                 const int* __restrict__ slot_tok,
                                                 const unsigned* __restrict__ counts,
                                                 const unsigned* __restrict__ offsets,
                                                 ushort* __restrict__ h) {
    const int e   = blockIdx.z;
    const int cnt = (int)counts[e];
    const int m0  = blockIdx.y * 128;
    if (m0 >= cnt) return;
    const int mrem = cnt - m0;
    const int n0   = blockIdx.x * 128;
    const int base = (int)offsets[e] + m0;

    __shared__ __align__(16) char lds[34816];   // A:16K | B:16K ; epilogue C: 128x272B
    char* ldsA = lds;
    char* ldsB = lds + 16384;

    const int tid  = threadIdx.x;
    const int lane = tid & 63;
    const int wid  = tid >> 6;
    const int wr = wid >> 1, wc = wid & 1;

    // staging: chunk p = (wid*4+i)*64 + lane; row r = p>>3; src chunk = (lane&7)^(lane>>3)
    const int cswz = ((lane & 7) ^ (lane >> 3)) * 8;   // ushort offset in row
    const ushort* pA[4];
    const ushort* pB[4];
    const ushort* w1te = w1t + (size_t)e * FF * DD;
    #pragma unroll
    for (int i = 0; i < 4; i++) {
        int r  = wid * 32 + i * 8 + (lane >> 3);
        int rr = (r < mrem) ? r : (mrem - 1);
        pA[i] = xb + (size_t)slot_tok[base + rr] * DD + cswz;
        pB[i] = w1te + (size_t)(n0 + r) * DD + cswz;
    }

    f32x4 acc[4][4] = {};

    for (int kt = 0; kt < DD / 64; ++kt) {
        __syncthreads();
        #pragma unroll
        for (int i = 0; i < 4; i++)
            gload_lds16(pA[i] + kt * 64, ldsA + (wid * 4 + i) * 1024);
        #pragma unroll
        for (int i = 0; i < 4; i++)
            gload_lds16(pB[i] + kt * 64, ldsB + (wid * 4 + i) * 1024);
        __syncthreads();
        #pragma unroll
        for (int kk = 0; kk < 2; ++kk) {
            bf16x8 a[4], b[4];
            #pragma unroll
            for (int m = 0; m < 4; m++) {
                int r = wr * 64 + m * 16 + (lane & 15);
                a[m] = *(const bf16x8*)(ldsA + ((r * 128 + kk * 64 + (lane >> 4) * 16) ^ ((r & 7) << 4)));
            }
            #pragma unroll
            for (int n = 0; n < 4; n++) {
                int r = wc * 64 + n * 16 + (lane & 15);
                b[n] = *(const bf16x8*)(ldsB + ((r * 128 + kk * 64 + (lane >> 4) * 16) ^ ((r & 7) << 4)));
            }
            #pragma unroll
            for (int m = 0; m < 4; m++)
                #pragma unroll
                for (int n = 0; n < 4; n++)
                    acc[m][n] = __builtin_amdgcn_mfma_f32_16x16x32_bf16(a[m], b[n], acc[m][n], 0, 0, 0);
        }
    }

    // epilogue: bias + exact gelu -> LDS repack (stride 272B) -> coalesced 16B stores
    __syncthreads();
    const float* b1e = b1 + (size_t)e * FF + n0;
    ushort* ldsC = (ushort*)lds;
    #pragma unroll
    for (int m = 0; m < 4; m++) {
        #pragma unroll
        for (int n = 0; n < 4; n++) {
            int c = wc * 64 + n * 16 + (lane & 15);
            float bias = b1e[c];
            #pragma unroll
            for (int v = 0; v < 4; v++) {
                int lr = wr * 64 + m * 16 + (lane >> 4) * 4 + v;
                float val = acc[m][n][v] + bias;
                val = 0.5f * val * (1.0f + erff(val * 0.70710678118654752f));
                ldsC[lr * 136 + c] = f2bf(val);
            }
        }
    }
    __syncthreads();
    #pragma unroll
    for (int i = 0; i < 8; i++) {
        int p = tid + i * 256;         // 16B chunks: 128 rows x 16 chunks
        int r = p >> 4, c16 = p & 15;
        if (r < mrem) {
            uint4 v = *(const uint4*)(lds + r * 272 + c16 * 16);
            *(uint4*)(h + (size_t)(base + r) * FF + n0 + c16 * 8) = v;
        }
    }
}

// ---------------- FFN2: out[tok] += w * (h @ w2t^T + b2) ----------------
__global__ __launch_bounds__(256, 2) void k_ffn2(const ushort* __restrict__ h,
                                                 const ushort* __restrict__ w2t,  // [E][D][F] bf16
                                                 const float* __restrict__ b2,
                                                 const int* __restrict__ slot_tok,
                                                 const float* __restrict__ slot_w,
                                                 const unsigned* __restrict__ counts,
                                                 const unsigned* __restrict__ offsets,
                                                 float* __restrict__ out) {
    const int e   = blockIdx.z;
    const int cnt = (int)counts[e];
    const int m0  = blockIdx.y * 128;
    if (m0 >= cnt) return;
    const int mrem = cnt - m0;
    const int n0   = blockIdx.x * 128;
    const int base = (int)offsets[e] + m0;

    __shared__ __align__(16) char lds[32768];
    char* ldsA = lds;
    char* ldsB = lds + 16384;

    const int tid  = threadIdx.x;
    const int lane = tid & 63;
    const int wid  = tid >> 6;
    const int wr = wid >> 1, wc = wid & 1;

    const int cswz = ((lane & 7) ^ (lane >> 3)) * 8;
    const ushort* pA[4];
    const ushort* pB[4];
    const ushort* w2te = w2t + (size_t)e * DD * FF;
    #pragma unroll
    for (int i = 0; i < 4; i++) {
        int r  = wid * 32 + i * 8 + (lane >> 3);
        int rr = (r < mrem) ? r : (mrem - 1);
        pA[i] = h + (size_t)(base + rr) * FF + cswz;
        pB[i] = w2te + (size_t)(n0 + r) * FF + cswz;
    }

    f32x4 acc[4][4] = {};

    for (int kt = 0; kt < FF / 64; ++kt) {
        __syncthreads();
        #pragma unroll
        for (int i = 0; i < 4; i++)
            gload_lds16(pA[i] + kt * 64, ldsA + (wid * 4 + i) * 1024);
        #pragma unroll
        for (int i = 0; i < 4; i++)
            gload_lds16(pB[i] + kt * 64, ldsB + (wid * 4 + i) * 1024);
        __syncthreads();
        #pragma unroll
        for (int kk = 0; kk < 2; ++kk) {
            bf16x8 a[4], b[4];
            #pragma unroll
            for (int m = 0; m < 4; m++) {
                int r = wr * 64 + m * 16 + (lane & 15);
                a[m] = *(const bf16x8*)(ldsA + ((r * 128 + kk * 64 + (lane >> 4) * 16) ^ ((r & 7) << 4)));
            }
            #pragma unroll
            for (int n = 0; n < 4; n++) {
                int r = wc * 64 + n * 16 + (lane & 15);
                b[n] = *(const bf16x8*)(ldsB + ((r * 128 + kk * 64 + (lane >> 4) * 16) ^ ((r & 7) << 4)));
            }
            #pragma unroll
            for (int m = 0; m < 4; m++)
                #pragma unroll
                for (int n = 0; n < 4; n++)
                    acc[m][n] = __builtin_amdgcn_mfma_f32_16x16x32_bf16(a[m], b[n], acc[m][n], 0, 0, 0);
        }
    }

    const float* b2e = b2 + (size_t)e * DD + n0;
    #pragma unroll
    for (int m = 0; m < 4; m++) {
        #pragma unroll
        for (int v = 0; v < 4; v++) {
            int lr = wr * 64 + m * 16 + (lane >> 4) * 4 + v;
            if (lr < mrem) {
                int slot = base + lr;
                int tok  = slot_tok[slot];
                float wgt = slot_w[slot];
                float* orow = out + (size_t)tok * DD + n0;
                #pragma unroll
                for (int n = 0; n < 4; n++) {
                    int c = wc * 64 + n * 16 + (lane & 15);
                    atomicAdd(orow + c, wgt * (acc[m][n][v] + b2e[c]));
                }
            }
        }
    }
}

// ---------------- aux loss ----------------
__global__ void k_aux(const float* __restrict__ sumpart, float* __restrict__ out_aux) {
    __shared__ float col[8];
    int tid = threadIdx.x;  // 64
    if (tid < 8) col[tid] = 0.f;
    __syncthreads();
    #pragma unroll
    for (int e = 0; e < 8; e++) atomicAdd(&col[e], sumpart[tid * 8 + e]);
    __syncthreads();
    if (tid == 0) {
        float aux = 0.f;
        for (int e = 0; e < 8; e++) {
            float d = col[e] * (1.0f / NTOK) - 0.125f;
            aux += d * d;
        }
        out_aux[0] = aux;
    }
}

extern "C" void kernel_launch(void* const* d_in, const int* in_sizes, int n_in,
                              void* d_out, int out_size, void* d_ws, size_t ws_size,
                              hipStream_t stream) {
    const float* x  = (const float*)d_in[0];
    const float* gw = (const float*)d_in[1];
    const float* w1 = (const float*)d_in[2];
    const float* b1 = (const float*)d_in[3];
    const float* w2 = (const float*)d_in[4];
    const float* b2 = (const float*)d_in[5];
    float* out = (float*)d_out;
    char*  ws  = (char*)d_ws;

    unsigned* counts  = (unsigned*)(ws + WS_COUNTS);
    unsigned* cursors = (unsigned*)(ws + WS_CURSORS);
    unsigned* offsets = (unsigned*)(ws + WS_OFFSETS);
    float*    sumpart = (float*)   (ws + WS_SUMPART);
    float4*   toktop  = (float4*)  (ws + WS_TOKTOP);
    int*      slottok = (int*)     (ws + WS_SLOTTOK);
    float*    slotw   = (float*)   (ws + WS_SLOTW);
    ushort*   xb      = (ushort*)  (ws + WS_XBF);
    ushort*   w1t     = (ushort*)  (ws + WS_W1T);
    ushort*   w2t     = (ushort*)  (ws + WS_W2T);
    ushort*   hbuf    = (ushort*)  (ws + WS_H);

    hipMemsetAsync(ws, 0, 4096, stream);
    hipMemsetAsync(d_out, 0, (size_t)out_size * sizeof(float), stream);

    // weight transposes (independent of router chain)
    k_transpose<<<dim3(FF / 64, DD / 64, EE), 256, 0, stream>>>(w1, w1t, DD, FF);
    k_transpose<<<dim3(DD / 64, FF / 64, EE), 256, 0, stream>>>(w2, w2t, FF, DD);

    k_convert_x<<<2048, 256, 0, stream>>>(x, xb);
    k_router  <<<NTOK / 4, 256, 0, stream>>>(x, gw, toktop, counts, sumpart);
    k_offsets <<<1, 64, 0, stream>>>(counts, offsets);
    k_scatter <<<NTOK / 256, 256, 0, stream>>>(toktop, offsets, cursors, slottok, slotw);
    k_ffn1    <<<dim3(FF / 128, NTOK / 128, EE), 256, 0, stream>>>(xb, w1t, b1, slottok, counts, offsets, hbuf);
    k_ffn2    <<<dim3(DD / 128, NTOK / 128, EE), 256, 0, stream>>>(hbuf, w2t, b2, slottok, slotw, counts, offsets, out);
    k_aux     <<<1, 64, 0, stream>>>(sumpart, out + (size_t)NTOK * DD);
}

// Round 3
// 847.533 us; speedup vs baseline: 2.5230x; 1.0162x over previous
//
#include <hip/hip_runtime.h>
#include <hip/hip_bf16.h>
#include <cstdint>
#include <cstddef>

// Problem constants (B=4,T=2048 -> 8192 tokens)
#define DD   1024
#define FF   4096
#define EE   8
#define NTOK 8192
#define PAIRS (NTOK*2)

typedef short bf16x8 __attribute__((ext_vector_type(8)));
typedef float f32x4  __attribute__((ext_vector_type(4)));

// ---- workspace layout (bytes). Total ~285 MB ----
#define WS_COUNTS   0
#define WS_CURSORS  64
#define WS_OFFSETS  128
#define WS_SUMPART  256
#define WS_TOKTOP   4096
#define WS_SLOTTOK  (WS_TOKTOP + NTOK*16)             // 135168
#define WS_SLOTW    (WS_SLOTTOK + PAIRS*4)            // 200704
#define WS_XBF      (WS_SLOTW + PAIRS*4)              // 266240
#define WS_W1T      (WS_XBF + (size_t)NTOK*DD*2)      // +16 MB
#define WS_W2T      (WS_W1T + (size_t)EE*DD*FF*2)     // +67 MB
#define WS_H        (WS_W2T + (size_t)EE*FF*DD*2)     // +67 MB (h: +134 MB)

__device__ __forceinline__ unsigned short f2bf(float f) {
    union { float f; unsigned u; } v; v.f = f;
    unsigned r = v.u + 0x7fffu + ((v.u >> 16) & 1u);   // RNE
    return (unsigned short)(r >> 16);
}

__device__ __forceinline__ void gload_lds16(const void* g, void* l) {
    __builtin_amdgcn_global_load_lds(
        (const __attribute__((address_space(1))) void*)g,
        (__attribute__((address_space(3))) void*)l, 16, 0, 0);
}

// ---------------- x fp32 -> bf16 ----------------
__global__ __launch_bounds__(256) void k_convert_x(const float* __restrict__ x,
                                                   ushort* __restrict__ xb) {
    int n4 = NTOK * DD / 4;
    int i = blockIdx.x * 256 + threadIdx.x;
    int stride = gridDim.x * 256;
    for (; i < n4; i += stride) {
        float4 v = ((const float4*)x)[i];
        ushort4 o;
        o.x = f2bf(v.x); o.y = f2bf(v.y); o.z = f2bf(v.z); o.w = f2bf(v.w);
        ((ushort4*)xb)[i] = o;
    }
}

// ---------------- weight transpose: [E][R][C] fp32 -> [E][C][R] bf16 ----------------
__global__ __launch_bounds__(256) void k_transpose(const float* __restrict__ in,
                                                   ushort* __restrict__ out,
                                                   int R, int C) {
    __shared__ ushort tile[64 * 72];   // row stride 72 ushorts = 144B (16B aligned)
    const int e = blockIdx.z;
    const int r0 = blockIdx.y * 64, c0 = blockIdx.x * 64;
    const int t = threadIdx.x;
    {
        const float* src = in + ((size_t)e * R + r0) * C + c0;
        int r = t >> 2, cq = (t & 3) * 16;
        #pragma unroll
        for (int j = 0; j < 4; j++) {
            float4 v = *(const float4*)(src + (size_t)r * C + cq + j * 4);
            ushort4 o;
            o.x = f2bf(v.x); o.y = f2bf(v.y); o.z = f2bf(v.z); o.w = f2bf(v.w);
            *(ushort4*)(tile + r * 72 + cq + j * 4) = o;
        }
    }
    __syncthreads();
    {
        int c = t >> 2, rq = (t & 3) * 16;
        ushort* dst = out + ((size_t)e * C + c0 + c) * R + r0 + rq;
        ushort buf[16];
        #pragma unroll
        for (int j = 0; j < 16; j++) buf[j] = tile[(rq + j) * 72 + c];
        *(uint4*)(dst)     = *(const uint4*)(buf);
        *(uint4*)(dst + 8) = *(const uint4*)(buf + 8);
    }
}

// ---------------- router: logits -> softmax -> top2 ----------------
__global__ __launch_bounds__(256) void k_router(const float* __restrict__ x,
                                                const float* __restrict__ gw,
                                                float4* __restrict__ toktop,
                                                unsigned* __restrict__ counts,
                                                float* __restrict__ sumpart) {
    __shared__ float bsum[8];
    __shared__ unsigned bcnt[8];
    int lane = threadIdx.x & 63;
    int wid  = threadIdx.x >> 6;
    if (threadIdx.x < 8) { bsum[threadIdx.x] = 0.f; bcnt[threadIdx.x] = 0u; }
    __syncthreads();

    int t = blockIdx.x * 4 + wid;
    float p[8] = {0,0,0,0,0,0,0,0};
    const float* xr = x + (size_t)t * DD;
    #pragma unroll
    for (int j = 0; j < 16; j++) {
        int d = lane + j * 64;
        float xv = xr[d];
        const float4 g0 = ((const float4*)(gw + (size_t)d * 8))[0];
        const float4 g1 = ((const float4*)(gw + (size_t)d * 8))[1];
        p[0] += xv * g0.x; p[1] += xv * g0.y; p[2] += xv * g0.z; p[3] += xv * g0.w;
        p[4] += xv * g1.x; p[5] += xv * g1.y; p[6] += xv * g1.z; p[7] += xv * g1.w;
    }
    #pragma unroll
    for (int e = 0; e < 8; e++)
        #pragma unroll
        for (int off = 32; off; off >>= 1) p[e] += __shfl_xor(p[e], off);

    float mx = p[0];
    #pragma unroll
    for (int e = 1; e < 8; e++) mx = fmaxf(mx, p[e]);
    float s = 0.f;
    #pragma unroll
    for (int e = 0; e < 8; e++) { p[e] = expf(p[e] - mx); s += p[e]; }
    float inv = 1.f / s;
    #pragma unroll
    for (int e = 0; e < 8; e++) p[e] *= inv;

    int i0 = 0; float p0 = p[0];
    #pragma unroll
    for (int e = 1; e < 8; e++) if (p[e] > p0) { p0 = p[e]; i0 = e; }
    int i1 = (i0 == 0) ? 1 : 0; float p1 = p[i1];
    #pragma unroll
    for (int e = 0; e < 8; e++) if (e != i0 && p[e] > p1) { p1 = p[e]; i1 = e; }

    if (lane == 0) {
        float wsum = p0 + p1 + 1e-9f;
        float4 tt;
        tt.x = p0 / wsum; tt.y = p1 / wsum;
        tt.z = __int_as_float(i0); tt.w = __int_as_float(i1);
        toktop[t] = tt;
        atomicAdd(&bcnt[i0], 1u);
        atomicAdd(&bcnt[i1], 1u);
        #pragma unroll
        for (int e = 0; e < 8; e++) atomicAdd(&bsum[e], p[e]);
    }
    __syncthreads();
    if (threadIdx.x < 8) {
        atomicAdd(&sumpart[(blockIdx.x & 63) * 8 + threadIdx.x], bsum[threadIdx.x]);
        if (bcnt[threadIdx.x]) atomicAdd(&counts[threadIdx.x], bcnt[threadIdx.x]);
    }
}

// ---------------- offsets ----------------
__global__ void k_offsets(const unsigned* __restrict__ counts, unsigned* __restrict__ offsets) {
    if (threadIdx.x == 0) {
        unsigned o = 0;
        for (int e = 0; e < 8; e++) { offsets[e] = o; o += counts[e]; }
    }
}

// ---------------- scatter ----------------
__global__ __launch_bounds__(256) void k_scatter(const float4* __restrict__ toktop,
                                                 const unsigned* __restrict__ offsets,
                                                 unsigned* __restrict__ cursors,
                                                 int* __restrict__ slot_tok,
                                                 float* __restrict__ slot_w) {
    int t = blockIdx.x * 256 + threadIdx.x;
    int lane = threadIdx.x & 63;
    float4 tt = toktop[t];
    int   idx[2] = { __float_as_int(tt.z), __float_as_int(tt.w) };
    float wv[2]  = { tt.x, tt.y };
    #pragma unroll
    for (int k = 0; k < 2; k++) {
        int e = idx[k];
        #pragma unroll
        for (int ee = 0; ee < 8; ee++) {
            unsigned long long m = __ballot(e == ee);
            if (e == ee) {
                int leader = __builtin_ctzll(m);
                int prefix = __popcll(m & ((1ull << lane) - 1ull));
                unsigned b = 0;
                if (lane == leader) b = atomicAdd(&cursors[ee], (unsigned)__popcll(m));
                b = __shfl(b, leader);
                int slot = (int)offsets[ee] + (int)b + prefix;
                slot_tok[slot] = t;
                slot_w[slot]   = wv[k];
            }
        }
    }
}

// ---------------- FFN1: h = gelu(gather(xb) @ w1t^T + b1) ----------------
// 128x128 tile, BK=64, 4 waves (2x2), global_load_lds staging (pre-swizzled src)
// XCD-chunked swizzle: each XCD owns a contiguous logical range, n-fastest (A-panel reuse in L2)
__global__ __launch_bounds__(256, 4) void k_ffn1(const ushort* __restrict__ xb,
                                                 const ushort* __restrict__ w1t,  // [E][F][D] bf16
                                                 const float* __restrict__ b1,
                                                 const int* __restrict__ slot_tok,
                                                 const unsigned* __restrict__ counts,
                                                 const unsigned* __restrict__ offsets,
                                                 ushort* __restrict__ h) {
    // grid = dim3(32, 64, 8); NWG = 16384
    const int L   = blockIdx.x + 32 * (blockIdx.y + 64 * blockIdx.z);
    const int swz = (L & 7) * (16384 / 8) + (L >> 3);
    const int e   = swz >> 11;          // / (32*64)
    const int rem = swz & 2047;
    const int mt  = rem >> 5;           // / 32
    const int nt  = rem & 31;

    const int cnt = (int)counts[e];
    const int m0  = mt * 128;
    if (m0 >= cnt) return;
    const int mrem = cnt - m0;
    const int n0   = nt * 128;
    const int base = (int)offsets[e] + m0;

    __shared__ __align__(16) char lds[34816];   // A:16K | B:16K ; epilogue C: 128x272B
    char* ldsA = lds;
    char* ldsB = lds + 16384;

    const int tid  = threadIdx.x;
    const int lane = tid & 63;
    const int wid  = tid >> 6;
    const int wr = wid >> 1, wc = wid & 1;

    // staging: chunk p = (wid*4+i)*64 + lane; row r = p>>3; src chunk = (lane&7)^(lane>>3)
    const int cswz = ((lane & 7) ^ (lane >> 3)) * 8;   // ushort offset in row
    const ushort* pA[4];
    const ushort* pB[4];
    const ushort* w1te = w1t + (size_t)e * FF * DD;
    #pragma unroll
    for (int i = 0; i < 4; i++) {
        int r  = wid * 32 + i * 8 + (lane >> 3);
        int rr = (r < mrem) ? r : (mrem - 1);
        pA[i] = xb + (size_t)slot_tok[base + rr] * DD + cswz;
        pB[i] = w1te + (size_t)(n0 + r) * DD + cswz;
    }

    f32x4 acc[4][4] = {};

    for (int kt = 0; kt < DD / 64; ++kt) {
        __syncthreads();
        #pragma unroll
        for (int i = 0; i < 4; i++)
            gload_lds16(pA[i] + kt * 64, ldsA + (wid * 4 + i) * 1024);
        #pragma unroll
        for (int i = 0; i < 4; i++)
            gload_lds16(pB[i] + kt * 64, ldsB + (wid * 4 + i) * 1024);
        __syncthreads();
        #pragma unroll
        for (int kk = 0; kk < 2; ++kk) {
            bf16x8 a[4], b[4];
            #pragma unroll
            for (int m = 0; m < 4; m++) {
                int r = wr * 64 + m * 16 + (lane & 15);
                a[m] = *(const bf16x8*)(ldsA + ((r * 128 + kk * 64 + (lane >> 4) * 16) ^ ((r & 7) << 4)));
            }
            #pragma unroll
            for (int n = 0; n < 4; n++) {
                int r = wc * 64 + n * 16 + (lane & 15);
                b[n] = *(const bf16x8*)(ldsB + ((r * 128 + kk * 64 + (lane >> 4) * 16) ^ ((r & 7) << 4)));
            }
            #pragma unroll
            for (int m = 0; m < 4; m++)
                #pragma unroll
                for (int n = 0; n < 4; n++)
                    acc[m][n] = __builtin_amdgcn_mfma_f32_16x16x32_bf16(a[m], b[n], acc[m][n], 0, 0, 0);
        }
    }

    // epilogue: bias + exact gelu -> LDS repack (stride 272B) -> coalesced 16B stores
    __syncthreads();
    const float* b1e = b1 + (size_t)e * FF + n0;
    ushort* ldsC = (ushort*)lds;
    #pragma unroll
    for (int m = 0; m < 4; m++) {
        #pragma unroll
        for (int n = 0; n < 4; n++) {
            int c = wc * 64 + n * 16 + (lane & 15);
            float bias = b1e[c];
            #pragma unroll
            for (int v = 0; v < 4; v++) {
                int lr = wr * 64 + m * 16 + (lane >> 4) * 4 + v;
                float val = acc[m][n][v] + bias;
                val = 0.5f * val * (1.0f + erff(val * 0.70710678118654752f));
                ldsC[lr * 136 + c] = f2bf(val);
            }
        }
    }
    __syncthreads();
    #pragma unroll
    for (int i = 0; i < 8; i++) {
        int p = tid + i * 256;         // 16B chunks: 128 rows x 16 chunks
        int r = p >> 4, c16 = p & 15;
        if (r < mrem) {
            uint4 v = *(const uint4*)(lds + r * 272 + c16 * 16);
            *(uint4*)(h + (size_t)(base + r) * FF + n0 + c16 * 8) = v;
        }
    }
}

// ---------------- FFN2: out[tok] += w * (h @ w2t^T + b2) ----------------
__global__ __launch_bounds__(256, 4) void k_ffn2(const ushort* __restrict__ h,
                                                 const ushort* __restrict__ w2t,  // [E][D][F] bf16
                                                 const float* __restrict__ b2,
                                                 const int* __restrict__ slot_tok,
                                                 const float* __restrict__ slot_w,
                                                 const unsigned* __restrict__ counts,
                                                 const unsigned* __restrict__ offsets,
                                                 float* __restrict__ out) {
    // grid = dim3(8, 64, 8); NWG = 4096
    const int L   = blockIdx.x + 8 * (blockIdx.y + 64 * blockIdx.z);
    const int swz = (L & 7) * (4096 / 8) + (L >> 3);
    const int e   = swz >> 9;           // / (8*64)
    const int rem = swz & 511;
    const int mt  = rem >> 3;
    const int nt  = rem & 7;

    const int cnt = (int)counts[e];
    const int m0  = mt * 128;
    if (m0 >= cnt) return;
    const int mrem = cnt - m0;
    const int n0   = nt * 128;
    const int base = (int)offsets[e] + m0;

    __shared__ __align__(16) char lds[32768];
    char* ldsA = lds;
    char* ldsB = lds + 16384;

    const int tid  = threadIdx.x;
    const int lane = tid & 63;
    const int wid  = tid >> 6;
    const int wr = wid >> 1, wc = wid & 1;

    const int cswz = ((lane & 7) ^ (lane >> 3)) * 8;
    const ushort* pA[4];
    const ushort* pB[4];
    const ushort* w2te = w2t + (size_t)e * DD * FF;
    #pragma unroll
    for (int i = 0; i < 4; i++) {
        int r  = wid * 32 + i * 8 + (lane >> 3);
        int rr = (r < mrem) ? r : (mrem - 1);
        pA[i] = h + (size_t)(base + rr) * FF + cswz;
        pB[i] = w2te + (size_t)(n0 + r) * FF + cswz;
    }

    f32x4 acc[4][4] = {};

    for (int kt = 0; kt < FF / 64; ++kt) {
        __syncthreads();
        #pragma unroll
        for (int i = 0; i < 4; i++)
            gload_lds16(pA[i] + kt * 64, ldsA + (wid * 4 + i) * 1024);
        #pragma unroll
        for (int i = 0; i < 4; i++)
            gload_lds16(pB[i] + kt * 64, ldsB + (wid * 4 + i) * 1024);
        __syncthreads();
        #pragma unroll
        for (int kk = 0; kk < 2; ++kk) {
            bf16x8 a[4], b[4];
            #pragma unroll
            for (int m = 0; m < 4; m++) {
                int r = wr * 64 + m * 16 + (lane & 15);
                a[m] = *(const bf16x8*)(ldsA + ((r * 128 + kk * 64 + (lane >> 4) * 16) ^ ((r & 7) << 4)));
            }
            #pragma unroll
            for (int n = 0; n < 4; n++) {
                int r = wc * 64 + n * 16 + (lane & 15);
                b[n] = *(const bf16x8*)(ldsB + ((r * 128 + kk * 64 + (lane >> 4) * 16) ^ ((r & 7) << 4)));
            }
            #pragma unroll
            for (int m = 0; m < 4; m++)
                #pragma unroll
                for (int n = 0; n < 4; n++)
                    acc[m][n] = __builtin_amdgcn_mfma_f32_16x16x32_bf16(a[m], b[n], acc[m][n], 0, 0, 0);
        }
    }

    const float* b2e = b2 + (size_t)e * DD + n0;
    #pragma unroll
    for (int m = 0; m < 4; m++) {
        #pragma unroll
        for (int v = 0; v < 4; v++) {
            int lr = wr * 64 + m * 16 + (lane >> 4) * 4 + v;
            if (lr < mrem) {
                int slot = base + lr;
                int tok  = slot_tok[slot];
                float wgt = slot_w[slot];
                float* orow = out + (size_t)tok * DD + n0;
                #pragma unroll
                for (int n = 0; n < 4; n++) {
                    int c = wc * 64 + n * 16 + (lane & 15);
                    atomicAdd(orow + c, wgt * (acc[m][n][v] + b2e[c]));
                }
            }
        }
    }
}

// ---------------- aux loss ----------------
__global__ void k_aux(const float* __restrict__ sumpart, float* __restrict__ out_aux) {
    __shared__ float col[8];
    int tid = threadIdx.x;  // 64
    if (tid < 8) col[tid] = 0.f;
    __syncthreads();
    #pragma unroll
    for (int e = 0; e < 8; e++) atomicAdd(&col[e], sumpart[tid * 8 + e]);
    __syncthreads();
    if (tid == 0) {
        float aux = 0.f;
        for (int e = 0; e < 8; e++) {
            float d = col[e] * (1.0f / NTOK) - 0.125f;
            aux += d * d;
        }
        out_aux[0] = aux;
    }
}

extern "C" void kernel_launch(void* const* d_in, const int* in_sizes, int n_in,
                              void* d_out, int out_size, void* d_ws, size_t ws_size,
                              hipStream_t stream) {
    const float* x  = (const float*)d_in[0];
    const float* gw = (const float*)d_in[1];
    const float* w1 = (const float*)d_in[2];
    const float* b1 = (const float*)d_in[3];
    const float* w2 = (const float*)d_in[4];
    const float* b2 = (const float*)d_in[5];
    float* out = (float*)d_out;
    char*  ws  = (char*)d_ws;

    unsigned* counts  = (unsigned*)(ws + WS_COUNTS);
    unsigned* cursors = (unsigned*)(ws + WS_CURSORS);
    unsigned* offsets = (unsigned*)(ws + WS_OFFSETS);
    float*    sumpart = (float*)   (ws + WS_SUMPART);
    float4*   toktop  = (float4*)  (ws + WS_TOKTOP);
    int*      slottok = (int*)     (ws + WS_SLOTTOK);
    float*    slotw   = (float*)   (ws + WS_SLOTW);
    ushort*   xb      = (ushort*)  (ws + WS_XBF);
    ushort*   w1t     = (ushort*)  (ws + WS_W1T);
    ushort*   w2t     = (ushort*)  (ws + WS_W2T);
    ushort*   hbuf    = (ushort*)  (ws + WS_H);

    hipMemsetAsync(ws, 0, 4096, stream);
    hipMemsetAsync(d_out, 0, (size_t)out_size * sizeof(float), stream);

    // weight transposes (independent of router chain)
    k_transpose<<<dim3(FF / 64, DD / 64, EE), 256, 0, stream>>>(w1, w1t, DD, FF);
    k_transpose<<<dim3(DD / 64, FF / 64, EE), 256, 0, stream>>>(w2, w2t, FF, DD);

    k_convert_x<<<2048, 256, 0, stream>>>(x, xb);
    k_router  <<<NTOK / 4, 256, 0, stream>>>(x, gw, toktop, counts, sumpart);
    k_offsets <<<1, 64, 0, stream>>>(counts, offsets);
    k_scatter <<<NTOK / 256, 256, 0, stream>>>(toktop, offsets, cursors, slottok, slotw);
    k_ffn1    <<<dim3(FF / 128, NTOK / 128, EE), 256, 0, stream>>>(xb, w1t, b1, slottok, counts, offsets, hbuf);
    k_ffn2    <<<dim3(DD / 128, NTOK / 128, EE), 256, 0, stream>>>(hbuf, w2t, b2, slottok, slotw, counts, offsets, out);
    k_aux     <<<1, 64, 0, stream>>>(sumpart, out + (size_t)NTOK * DD);
}